// Round 1
// baseline (389.852 us; speedup 1.0000x reference)
//
#include <hip/hip_runtime.h>
#include <cstdint>
#include <cstddef>

// Problem constants: B=8, S=2048, H=512, M=4096 -> R = B*S = 16384 rows.
#define R_TOTAL 16384
#define H_DIM   512
#define M_DIM   4096

typedef unsigned short u16;
typedef short bf16x8 __attribute__((ext_vector_type(8)));   // 8 bf16 in 4 VGPRs
typedef float f32x4  __attribute__((ext_vector_type(4)));

typedef const __attribute__((address_space(1))) void* gp_t;
typedef __attribute__((address_space(3))) void* lp_t;

// fp32 -> bf16 round-to-nearest-even
__device__ __forceinline__ u16 f2b(float f) {
  union { float f; uint32_t u; } v; v.f = f;
  uint32_t u = v.u + (0x7FFFu + ((v.u >> 16) & 1u));
  return (u16)(u >> 16);
}

// ---------------- elementwise fp32 -> bf16 (n4 = n/4 float4 groups) ----------
__global__ void k_f2bf(const float* __restrict__ in, u16* __restrict__ out, int n4) {
  int i = blockIdx.x * blockDim.x + threadIdx.x;
  if (i < n4) {
    float4 v = ((const float4*)in)[i];
    ushort4 o;
    o.x = f2b(v.x); o.y = f2b(v.y); o.z = f2b(v.z); o.w = f2b(v.w);
    ((ushort4*)out)[i] = o;
  }
}

// ------------- row L2-normalize: fp32 [rows,512] -> bf16 [rows,512] ----------
// one wave per row, 4 waves per block
__global__ void k_rownorm(const float* __restrict__ in, u16* __restrict__ out) {
  int row  = blockIdx.x * 4 + (threadIdx.x >> 6);
  int lane = threadIdx.x & 63;
  const float4* rp = (const float4*)(in + (size_t)row * H_DIM);
  float4 a = rp[lane];
  float4 b = rp[lane + 64];
  float ss = a.x*a.x + a.y*a.y + a.z*a.z + a.w*a.w
           + b.x*b.x + b.y*b.y + b.z*b.z + b.w*b.w;
  #pragma unroll
  for (int d = 1; d < 64; d <<= 1) ss += __shfl_xor(ss, d, 64);
  float s = rsqrtf(ss + 1e-6f);
  ushort4 oa, ob;
  oa.x = f2b(a.x*s); oa.y = f2b(a.y*s); oa.z = f2b(a.z*s); oa.w = f2b(a.w*s);
  ob.x = f2b(b.x*s); ob.y = f2b(b.y*s); ob.z = f2b(b.z*s); ob.w = f2b(b.w*s);
  ushort4* op = (ushort4*)(out + (size_t)row * H_DIM);
  op[lane]      = oa;
  op[lane + 64] = ob;
}

// ---- transpose + convert: V fp32 [4096,512] -> Vt bf16 [512,4096] -----------
__global__ void k_transpose_cvt(const float* __restrict__ in, u16* __restrict__ out) {
  __shared__ u16 tile[32][33];
  int tx = threadIdx.x & 31, ty = threadIdx.x >> 5;   // 32x8
  int m0 = blockIdx.y * 32, v0 = blockIdx.x * 32;
  #pragma unroll
  for (int j = 0; j < 4; ++j)
    tile[ty + j*8][tx] = f2b(in[(size_t)(m0 + ty + j*8) * H_DIM + v0 + tx]);
  __syncthreads();
  #pragma unroll
  for (int j = 0; j < 4; ++j)
    out[(size_t)(v0 + ty + j*8) * M_DIM + m0 + tx] = tile[tx][ty + j*8];
}

// ---- reduce partial row sums -> reciprocal ----------------------------------
__global__ void k_reduce_l(const float* __restrict__ lpart, float* __restrict__ linv, int npart) {
  int r = blockIdx.x * blockDim.x + threadIdx.x;
  float s = 0.0f;
  for (int i = 0; i < npart; ++i) s += lpart[(size_t)r * npart + i];
  linv[r] = 1.0f / s;
}

// =============================================================================
// BT-layout GEMM: C[r,n] = sum_k A[r,k] * B[n,k]   (A: [Rr,K] bf16, B: [N,K] bf16)
// 128x128 tile, BK=32, 256 threads = 4 waves, each wave 64x64 via 4x4 of 16x16x32.
// EPI 0: outf[r*N+n] = C + bias[n]                 (fp32 out)
// EPI 1: P = usage[n]>0 ? exp(10*C) : 0 -> outh bf16; per-row partial sums -> lpart
// EPI 2: outh bf16 = C * linv[r]
// =============================================================================
template<int EPI>
__global__ __launch_bounds__(256)
void k_gemm_bt(const u16* __restrict__ A, const u16* __restrict__ B,
               int N, int K,
               float* __restrict__ outf, u16* __restrict__ outh,
               const float* __restrict__ bias,
               const int* __restrict__ usage,
               float* __restrict__ lpart, int npart,
               const float* __restrict__ linv) {
  __shared__ u16 Ah[128 * 32];
  __shared__ u16 Bh[128 * 32];
  __shared__ float lsh[128];

  const int tid  = threadIdx.x;
  const int wave = tid >> 6, lane = tid & 63;
  const int row0 = blockIdx.y * 128, col0 = blockIdx.x * 128;
  const int wr = (wave >> 1) * 64, wc = (wave & 1) * 64;

  if (EPI == 1 && tid < 128) lsh[tid] = 0.0f;

  f32x4 acc[4][4];
  const f32x4 z = {0.0f, 0.0f, 0.0f, 0.0f};
  #pragma unroll
  for (int i = 0; i < 4; ++i)
    #pragma unroll
    for (int j = 0; j < 4; ++j) acc[i][j] = z;

  // staging: per wave, two issues each for A and B; each issue = 64 lanes x 16B
  // lane l covers row (l>>2), k-chunk (l&3)*8 within a 16-row x 32-col slab.
  const int srow  = lane >> 2;
  const int skoff = (lane & 3) * 8;
  const size_t aBase0 = (size_t)(row0 + wave * 16 + srow)      * (size_t)K + skoff;
  const size_t aBase1 = (size_t)(row0 + (wave + 4) * 16 + srow)* (size_t)K + skoff;
  const size_t bBase0 = (size_t)(col0 + wave * 16 + srow)      * (size_t)K + skoff;
  const size_t bBase1 = (size_t)(col0 + (wave + 4) * 16 + srow)* (size_t)K + skoff;
  u16* ldsA0 = &Ah[(wave)     * 512];
  u16* ldsA1 = &Ah[(wave + 4) * 512];
  u16* ldsB0 = &Bh[(wave)     * 512];
  u16* ldsB1 = &Bh[(wave + 4) * 512];

  const int fr = lane & 15;         // fragment row (A: m, B: n)
  const int fk = (lane >> 4) * 8;   // fragment k offset

  for (int k0 = 0; k0 < K; k0 += 32) {
    __syncthreads();   // prior iteration's LDS reads drained
    __builtin_amdgcn_global_load_lds((gp_t)(A + aBase0 + k0), (lp_t)ldsA0, 16, 0, 0);
    __builtin_amdgcn_global_load_lds((gp_t)(A + aBase1 + k0), (lp_t)ldsA1, 16, 0, 0);
    __builtin_amdgcn_global_load_lds((gp_t)(B + bBase0 + k0), (lp_t)ldsB0, 16, 0, 0);
    __builtin_amdgcn_global_load_lds((gp_t)(B + bBase1 + k0), (lp_t)ldsB1, 16, 0, 0);
    __syncthreads();   // staging drained (vmcnt(0) before barrier)

    bf16x8 af[4], bfv[4];
    #pragma unroll
    for (int i = 0; i < 4; ++i)
      af[i] = *(const bf16x8*)&Ah[(wr + i * 16 + fr) * 32 + fk];
    #pragma unroll
    for (int j = 0; j < 4; ++j)
      bfv[j] = *(const bf16x8*)&Bh[(wc + j * 16 + fr) * 32 + fk];

    #pragma unroll
    for (int i = 0; i < 4; ++i)
      #pragma unroll
      for (int j = 0; j < 4; ++j)
        acc[i][j] = __builtin_amdgcn_mfma_f32_16x16x32_bf16(af[i], bfv[j], acc[i][j], 0, 0, 0);
  }

  // Epilogue. C/D layout per 16x16 tile: col = lane&15, row = (lane>>4)*4 + reg.
  if (EPI == 0) {
    #pragma unroll
    for (int i = 0; i < 4; ++i) {
      int growb = row0 + wr + i * 16 + (lane >> 4) * 4;
      #pragma unroll
      for (int j = 0; j < 4; ++j) {
        int gcol = col0 + wc + j * 16 + fr;
        float bv = bias[gcol];
        #pragma unroll
        for (int r = 0; r < 4; ++r)
          outf[(size_t)(growb + r) * (size_t)N + gcol] = acc[i][j][r] + bv;
      }
    }
  } else if (EPI == 1) {
    #pragma unroll
    for (int i = 0; i < 4; ++i) {
      #pragma unroll
      for (int r = 0; r < 4; ++r) {
        int lrow = wr + i * 16 + (lane >> 4) * 4 + r;
        size_t grow = (size_t)(row0 + lrow);
        float s = 0.0f;
        #pragma unroll
        for (int j = 0; j < 4; ++j) {
          int gcol = col0 + wc + j * 16 + fr;
          float p = (usage[gcol] > 0) ? __expf(acc[i][j][r] * 10.0f) : 0.0f;
          outh[grow * (size_t)N + gcol] = f2b(p);
          s += p;
        }
        #pragma unroll
        for (int d = 1; d < 16; d <<= 1) s += __shfl_xor(s, d, 64);
        if (fr == 0) atomicAdd(&lsh[lrow], s);
      }
    }
    __syncthreads();
    if (tid < 128)
      lpart[(size_t)(row0 + tid) * npart + blockIdx.x] = lsh[tid];
  } else {  // EPI == 2
    #pragma unroll
    for (int i = 0; i < 4; ++i) {
      #pragma unroll
      for (int r = 0; r < 4; ++r) {
        int grow = row0 + wr + i * 16 + (lane >> 4) * 4 + r;
        float sc = linv[grow];
        #pragma unroll
        for (int j = 0; j < 4; ++j) {
          int gcol = col0 + wc + j * 16 + fr;
          outh[(size_t)grow * (size_t)N + gcol] = f2b(acc[i][j][r] * sc);
        }
      }
    }
  }
}

extern "C" void kernel_launch(void* const* d_in, const int* in_sizes, int n_in,
                              void* d_out, int out_size, void* d_ws, size_t ws_size,
                              hipStream_t stream) {
  const float* hidden = (const float*)d_in[0];   // [16384, 512]
  const float* mkeys  = (const float*)d_in[1];   // [4096, 512]
  const float* mvals  = (const float*)d_in[2];   // [4096, 512]
  const float* Wk     = (const float*)d_in[3];   // [512, 512]
  const float* bk     = (const float*)d_in[4];   // [512]
  const float* Wo     = (const float*)d_in[5];   // [512, 512]
  const float* bo     = (const float*)d_in[6];   // [512]
  const int*   usage  = (const int*)d_in[7];     // [4096]
  (void)in_sizes; (void)n_in; (void)out_size; (void)ws_size;

  char* ws = (char*)d_ws;
  u16*   hb    = (u16*)(ws + 0);           //  16,777,216  hidden bf16
  u16*   wkb   = (u16*)(ws + 16777216);    //     524,288  Wk bf16
  u16*   wob   = (u16*)(ws + 17301504);    //     524,288  Wo bf16
  u16*   mkn   = (u16*)(ws + 17825792);    //   4,194,304  normalized keys bf16
  u16*   vt    = (u16*)(ws + 22020096);    //   4,194,304  V^T bf16 [512,4096]
  u16*   qn    = (u16*)(ws + 26214400);    //  16,777,216  normalized q bf16
  float* q     = (float*)(ws + 42991616);  //  33,554,432  q fp32 (aliases P; dead before P written)
  u16*   P     = (u16*)(ws + 42991616);    // 134,217,728  exp-scores bf16 [16384,4096]
  float* lpart = (float*)(ws + 177209344); //   2,097,152  row-sum partials [16384,32]
  float* linv  = (float*)(ws + 179306496); //      65,536  1/rowsum [16384]
  u16*   retr  = (u16*)(ws + 179372032);   //  16,777,216  retrieved bf16
  // total: 196,149,248 bytes

  // prep: casts, normalizations, transpose
  k_f2bf<<<8192, 256, 0, stream>>>(hidden, hb, 2097152);
  k_f2bf<<<256, 256, 0, stream>>>(Wk, wkb, 65536);
  k_f2bf<<<256, 256, 0, stream>>>(Wo, wob, 65536);
  k_rownorm<<<1024, 256, 0, stream>>>(mkeys, mkn);                       // 4096 rows
  k_transpose_cvt<<<dim3(16, 128), 256, 0, stream>>>(mvals, vt);

  // q = hidden @ Wk^T + bk  (fp32 out)
  k_gemm_bt<0><<<dim3(4, 128), 256, 0, stream>>>(hb, wkb, 512, 512,
      q, nullptr, bk, nullptr, nullptr, 0, nullptr);
  // qn = rownorm(q) bf16
  k_rownorm<<<4096, 256, 0, stream>>>(q, qn);                            // 16384 rows

  // P = exp(10 * qn @ mkn^T) * mask, partial row sums
  k_gemm_bt<1><<<dim3(32, 128), 256, 0, stream>>>(qn, mkn, 4096, 512,
      nullptr, P, nullptr, usage, lpart, 32, nullptr);
  k_reduce_l<<<64, 256, 0, stream>>>(lpart, linv, 32);

  // retrieved = (P @ Vt^T) * linv[row]  bf16
  k_gemm_bt<2><<<dim3(4, 128), 256, 0, stream>>>(P, vt, 512, 4096,
      nullptr, retr, nullptr, nullptr, nullptr, 0, linv);

  // out = retrieved @ Wo^T + bo  (fp32)
  k_gemm_bt<0><<<dim3(4, 128), 256, 0, stream>>>(retr, wob, 512, 512,
      (float*)d_out, nullptr, bo, nullptr, nullptr, 0, nullptr);
}

// Round 2
// 341.394 us; speedup vs baseline: 1.1419x; 1.1419x over previous
//
#include <hip/hip_runtime.h>
#include <cstdint>
#include <cstddef>

// Problem constants: B=8, S=2048, H=512, M=4096 -> R = B*S = 16384 rows.
#define R_TOTAL 16384
#define H_DIM   512
#define M_DIM   4096

typedef unsigned short u16;
typedef short bf16x8 __attribute__((ext_vector_type(8)));   // 8 bf16 in 4 VGPRs
typedef float f32x4  __attribute__((ext_vector_type(4)));

typedef const __attribute__((address_space(1))) void* gp_t;
typedef __attribute__((address_space(3))) void* lp_t;

// fp32 -> bf16 round-to-nearest-even
__device__ __forceinline__ u16 f2b(float f) {
  union { float f; uint32_t u; } v; v.f = f;
  uint32_t u = v.u + (0x7FFFu + ((v.u >> 16) & 1u));
  return (u16)(u >> 16);
}

// ---------------- elementwise fp32 -> bf16 (n4 = n/4 float4 groups) ----------
__global__ void k_f2bf(const float* __restrict__ in, u16* __restrict__ out, int n4) {
  int i = blockIdx.x * blockDim.x + threadIdx.x;
  if (i < n4) {
    float4 v = ((const float4*)in)[i];
    ushort4 o;
    o.x = f2b(v.x); o.y = f2b(v.y); o.z = f2b(v.z); o.w = f2b(v.w);
    ((ushort4*)out)[i] = o;
  }
}

// ------------- row L2-normalize: fp32 [rows,512] -> bf16 [rows,512] ----------
// one wave per row, 4 waves per block
__global__ void k_rownorm(const float* __restrict__ in, u16* __restrict__ out) {
  int row  = blockIdx.x * 4 + (threadIdx.x >> 6);
  int lane = threadIdx.x & 63;
  const float4* rp = (const float4*)(in + (size_t)row * H_DIM);
  float4 a = rp[lane];
  float4 b = rp[lane + 64];
  float ss = a.x*a.x + a.y*a.y + a.z*a.z + a.w*a.w
           + b.x*b.x + b.y*b.y + b.z*b.z + b.w*b.w;
  #pragma unroll
  for (int d = 1; d < 64; d <<= 1) ss += __shfl_xor(ss, d, 64);
  float s = rsqrtf(ss + 1e-6f);
  ushort4 oa, ob;
  oa.x = f2b(a.x*s); oa.y = f2b(a.y*s); oa.z = f2b(a.z*s); oa.w = f2b(a.w*s);
  ob.x = f2b(b.x*s); ob.y = f2b(b.y*s); ob.z = f2b(b.z*s); ob.w = f2b(b.w*s);
  ushort4* op = (ushort4*)(out + (size_t)row * H_DIM);
  op[lane]      = oa;
  op[lane + 64] = ob;
}

// ---- compaction: scan usage[4096] -> idx map + meta -------------------------
// meta[0]=count, meta[1]=K_eff=round128(count), meta[2]=K_eff/32, meta[3]=K_eff/128
__global__ void k_compact(const int* __restrict__ usage, int* __restrict__ idx,
                          int* __restrict__ meta) {
  __shared__ int cnt[256];
  int t = threadIdx.x;
  int base = t * 16;
  int c = 0;
  #pragma unroll
  for (int i = 0; i < 16; ++i) c += (usage[base + i] > 0) ? 1 : 0;
  cnt[t] = c;
  __syncthreads();
  for (int d = 1; d < 256; d <<= 1) {           // inclusive Hillis-Steele scan
    int v = (t >= d) ? cnt[t - d] : 0;
    __syncthreads();
    cnt[t] += v;
    __syncthreads();
  }
  int pos = cnt[t] - c;                          // exclusive prefix
  for (int i = 0; i < 16; ++i)
    if (usage[base + i] > 0) idx[pos++] = base + i;
  if (t == 0) {
    int total = cnt[255];
    int keff = ((total + 127) >> 7) << 7;
    meta[0] = total; meta[1] = keff; meta[2] = keff >> 5; meta[3] = keff >> 7;
  }
}

// ---- gather + L2-normalize keys into compacted bank (zeros padding) ---------
__global__ void k_gather_norm(const float* __restrict__ in, const int* __restrict__ idx,
                              const int* __restrict__ meta, u16* __restrict__ out) {
  int j    = blockIdx.x * 4 + (threadIdx.x >> 6);
  int lane = threadIdx.x & 63;
  int count = meta[0];
  ushort4* op = (ushort4*)(out + (size_t)j * H_DIM);
  if (j >= count) {                 // wave-uniform
    ushort4 z = {0, 0, 0, 0};
    op[lane] = z; op[lane + 64] = z;
    return;
  }
  int src = idx[j];
  const float4* rp = (const float4*)(in + (size_t)src * H_DIM);
  float4 a = rp[lane];
  float4 b = rp[lane + 64];
  float ss = a.x*a.x + a.y*a.y + a.z*a.z + a.w*a.w
           + b.x*b.x + b.y*b.y + b.z*b.z + b.w*b.w;
  #pragma unroll
  for (int d = 1; d < 64; d <<= 1) ss += __shfl_xor(ss, d, 64);
  float s = rsqrtf(ss + 1e-6f);
  ushort4 oa, ob;
  oa.x = f2b(a.x*s); oa.y = f2b(a.y*s); oa.z = f2b(a.z*s); oa.w = f2b(a.w*s);
  ob.x = f2b(b.x*s); ob.y = f2b(b.y*s); ob.z = f2b(b.z*s); ob.w = f2b(b.w*s);
  op[lane]      = oa;
  op[lane + 64] = ob;
}

// ---- gather + transpose + convert: V fp32 rows -> Vt bf16 [512, 4096] -------
__global__ void k_gather_t(const float* __restrict__ in, const int* __restrict__ idx,
                           const int* __restrict__ meta, u16* __restrict__ out) {
  __shared__ u16 tile[32][33];
  int tx = threadIdx.x & 31, ty = threadIdx.x >> 5;   // 32x8
  int m0 = blockIdx.y * 32, v0 = blockIdx.x * 32;
  int count = meta[0];
  #pragma unroll
  for (int j = 0; j < 4; ++j) {
    int m = m0 + ty + j * 8;
    u16 val = 0;
    if (m < count) {
      int src = idx[m];
      val = f2b(in[(size_t)src * H_DIM + v0 + tx]);
    }
    tile[ty + j*8][tx] = val;
  }
  __syncthreads();
  #pragma unroll
  for (int j = 0; j < 4; ++j)
    out[(size_t)(v0 + ty + j*8) * M_DIM + m0 + tx] = tile[tx][ty + j*8];
}

// ---- reduce partial row sums -> reciprocal (dynamic npart from meta) --------
__global__ void k_reduce_l(const float* __restrict__ lpart, float* __restrict__ linv,
                           const int* __restrict__ meta) {
  int r = blockIdx.x * blockDim.x + threadIdx.x;
  int n = meta[3];
  float s = 0.0f;
  for (int i = 0; i < n; ++i) s += lpart[(size_t)r * 32 + i];
  linv[r] = 1.0f / s;
}

// =============================================================================
// BT-layout GEMM: C[r,n] = sum_k A[r,k] * B[n,k]   (A: [Rr,K] bf16, B: [N,K] bf16)
// 128x128 tile, BK=32, 256 threads = 4 waves, each wave 64x64 via 4x4 of 16x16x32.
// EPI 0: outf[r*N+n] = C + bias[n]                 (fp32 out); kiters = K/32
// EPI 1: early-exit col0>=meta[1]; P = (n<meta[0]) ? exp(10*C) : 0 -> outh bf16;
//        per-row partial sums -> lpart[row*32 + bx]; kiters = K/32
// EPI 2: outh bf16 = C * linv[r]; kiters = meta[2]  (K is the LDS/global stride)
// =============================================================================
template<int EPI>
__global__ __launch_bounds__(256)
void k_gemm_bt(const u16* __restrict__ A, const u16* __restrict__ B,
               int N, int K,
               const int* __restrict__ meta,
               float* __restrict__ outf, u16* __restrict__ outh,
               const float* __restrict__ bias,
               float* __restrict__ lpart,
               const float* __restrict__ linv) {
  __shared__ u16 Ah[128 * 32];
  __shared__ u16 Bh[128 * 32];
  __shared__ float lsh[128];

  const int tid  = threadIdx.x;
  const int wave = tid >> 6, lane = tid & 63;
  const int row0 = blockIdx.y * 128, col0 = blockIdx.x * 128;
  const int wr = (wave >> 1) * 64, wc = (wave & 1) * 64;

  int kiters;
  if (EPI == 1) {
    if (col0 >= meta[1]) return;     // uniform: whole block exits together
    kiters = K >> 5;
  } else if (EPI == 2) {
    kiters = meta[2];
  } else {
    kiters = K >> 5;
  }

  if (EPI == 1 && tid < 128) lsh[tid] = 0.0f;

  f32x4 acc[4][4];
  const f32x4 z = {0.0f, 0.0f, 0.0f, 0.0f};
  #pragma unroll
  for (int i = 0; i < 4; ++i)
    #pragma unroll
    for (int j = 0; j < 4; ++j) acc[i][j] = z;

  // staging: per wave, two issues each for A and B; each issue = 64 lanes x 16B
  const int srow  = lane >> 2;
  const int skoff = (lane & 3) * 8;
  const size_t aBase0 = (size_t)(row0 + wave * 16 + srow)      * (size_t)K + skoff;
  const size_t aBase1 = (size_t)(row0 + (wave + 4) * 16 + srow)* (size_t)K + skoff;
  const size_t bBase0 = (size_t)(col0 + wave * 16 + srow)      * (size_t)K + skoff;
  const size_t bBase1 = (size_t)(col0 + (wave + 4) * 16 + srow)* (size_t)K + skoff;
  u16* ldsA0 = &Ah[(wave)     * 512];
  u16* ldsA1 = &Ah[(wave + 4) * 512];
  u16* ldsB0 = &Bh[(wave)     * 512];
  u16* ldsB1 = &Bh[(wave + 4) * 512];

  const int fr = lane & 15;         // fragment row (A: m, B: n)
  const int fk = (lane >> 4) * 8;   // fragment k offset

  for (int it = 0; it < kiters; ++it) {
    const int k0 = it << 5;
    __syncthreads();   // prior iteration's LDS reads drained
    __builtin_amdgcn_global_load_lds((gp_t)(A + aBase0 + k0), (lp_t)ldsA0, 16, 0, 0);
    __builtin_amdgcn_global_load_lds((gp_t)(A + aBase1 + k0), (lp_t)ldsA1, 16, 0, 0);
    __builtin_amdgcn_global_load_lds((gp_t)(B + bBase0 + k0), (lp_t)ldsB0, 16, 0, 0);
    __builtin_amdgcn_global_load_lds((gp_t)(B + bBase1 + k0), (lp_t)ldsB1, 16, 0, 0);
    __syncthreads();   // staging drained (vmcnt(0) before barrier)

    bf16x8 af[4], bfv[4];
    #pragma unroll
    for (int i = 0; i < 4; ++i)
      af[i] = *(const bf16x8*)&Ah[(wr + i * 16 + fr) * 32 + fk];
    #pragma unroll
    for (int j = 0; j < 4; ++j)
      bfv[j] = *(const bf16x8*)&Bh[(wc + j * 16 + fr) * 32 + fk];

    #pragma unroll
    for (int i = 0; i < 4; ++i)
      #pragma unroll
      for (int j = 0; j < 4; ++j)
        acc[i][j] = __builtin_amdgcn_mfma_f32_16x16x32_bf16(af[i], bfv[j], acc[i][j], 0, 0, 0);
  }

  // Epilogue. C/D layout per 16x16 tile: col = lane&15, row = (lane>>4)*4 + reg.
  if (EPI == 0) {
    #pragma unroll
    for (int i = 0; i < 4; ++i) {
      int growb = row0 + wr + i * 16 + (lane >> 4) * 4;
      #pragma unroll
      for (int j = 0; j < 4; ++j) {
        int gcol = col0 + wc + j * 16 + fr;
        float bv = bias[gcol];
        #pragma unroll
        for (int r = 0; r < 4; ++r)
          outf[(size_t)(growb + r) * (size_t)N + gcol] = acc[i][j][r] + bv;
      }
    }
  } else if (EPI == 1) {
    const int count = meta[0];
    #pragma unroll
    for (int i = 0; i < 4; ++i) {
      #pragma unroll
      for (int r = 0; r < 4; ++r) {
        int lrow = wr + i * 16 + (lane >> 4) * 4 + r;
        size_t grow = (size_t)(row0 + lrow);
        float s = 0.0f;
        #pragma unroll
        for (int j = 0; j < 4; ++j) {
          int gcol = col0 + wc + j * 16 + fr;
          float p = (gcol < count) ? __expf(acc[i][j][r] * 10.0f) : 0.0f;
          outh[grow * (size_t)N + gcol] = f2b(p);
          s += p;
        }
        #pragma unroll
        for (int d = 1; d < 16; d <<= 1) s += __shfl_xor(s, d, 64);
        if (fr == 0) atomicAdd(&lsh[lrow], s);
      }
    }
    __syncthreads();
    if (tid < 128)
      lpart[(size_t)(row0 + tid) * 32 + blockIdx.x] = lsh[tid];
  } else {  // EPI == 2
    #pragma unroll
    for (int i = 0; i < 4; ++i) {
      #pragma unroll
      for (int r = 0; r < 4; ++r) {
        int grow = row0 + wr + i * 16 + (lane >> 4) * 4 + r;
        float sc = linv[grow];
        #pragma unroll
        for (int j = 0; j < 4; ++j) {
          int gcol = col0 + wc + j * 16 + fr;
          outh[(size_t)grow * (size_t)N + gcol] = f2b(acc[i][j][r] * sc);
        }
      }
    }
  }
}

extern "C" void kernel_launch(void* const* d_in, const int* in_sizes, int n_in,
                              void* d_out, int out_size, void* d_ws, size_t ws_size,
                              hipStream_t stream) {
  const float* hidden = (const float*)d_in[0];   // [16384, 512]
  const float* mkeys  = (const float*)d_in[1];   // [4096, 512]
  const float* mvals  = (const float*)d_in[2];   // [4096, 512]
  const float* Wk     = (const float*)d_in[3];   // [512, 512]
  const float* bk     = (const float*)d_in[4];   // [512]
  const float* Wo     = (const float*)d_in[5];   // [512, 512]
  const float* bo     = (const float*)d_in[6];   // [512]
  const int*   usage  = (const int*)d_in[7];     // [4096]
  (void)in_sizes; (void)n_in; (void)out_size; (void)ws_size;

  char* ws = (char*)d_ws;
  // hb region [0, 16 MB): bf16 hidden during q-chain; AFTER q-chain it is dead
  // and its first 16 KB + 16 B are reused for idx/meta (footprint unchanged).
  u16*   hb    = (u16*)(ws + 0);           //  16,777,216  hidden bf16 (early)
  int*   idx   = (int*)(ws + 0);           //      16,384  compacted->orig map (late)
  int*   meta  = (int*)(ws + 16384);       //          16  {count, K_eff, K_eff/32, K_eff/128}
  u16*   wkb   = (u16*)(ws + 16777216);    //     524,288  Wk bf16
  u16*   wob   = (u16*)(ws + 17301504);    //     524,288  Wo bf16
  u16*   mkn   = (u16*)(ws + 17825792);    //   4,194,304  compacted normalized keys bf16
  u16*   vt    = (u16*)(ws + 22020096);    //   4,194,304  compacted V^T bf16 [512,4096]
  u16*   qn    = (u16*)(ws + 26214400);    //  16,777,216  normalized q bf16
  float* q     = (float*)(ws + 42991616);  //  33,554,432  q fp32 (aliases P; dead before P written)
  u16*   P     = (u16*)(ws + 42991616);    // 134,217,728  exp-scores bf16 [16384,4096]
  float* lpart = (float*)(ws + 177209344); //   2,097,152  row-sum partials [16384,32]
  float* linv  = (float*)(ws + 179306496); //      65,536  1/rowsum [16384]
  u16*   retr  = (u16*)(ws + 179372032);   //  16,777,216  retrieved bf16
  // total: 196,149,248 bytes (same as previous passing round)

  // --- q-projection chain first (so hb can be reused for idx/meta) ---
  k_f2bf<<<8192, 256, 0, stream>>>(hidden, hb, 2097152);
  k_f2bf<<<256, 256, 0, stream>>>(Wk, wkb, 65536);
  k_f2bf<<<256, 256, 0, stream>>>(Wo, wob, 65536);

  // q = hidden @ Wk^T + bk  (fp32 out)
  k_gemm_bt<0><<<dim3(4, 128), 256, 0, stream>>>(hb, wkb, 512, 512,
      nullptr, q, nullptr, bk, nullptr, nullptr);
  // qn = rownorm(q) bf16
  k_rownorm<<<4096, 256, 0, stream>>>(q, qn);                            // 16384 rows

  // --- compaction of the memory bank (hb now dead) ---
  k_compact<<<1, 256, 0, stream>>>(usage, idx, meta);
  k_gather_norm<<<1024, 256, 0, stream>>>(mkeys, idx, meta, mkn);        // 4096 slots
  k_gather_t<<<dim3(16, 128), 256, 0, stream>>>(mvals, idx, meta, vt);

  // P = exp(10 * qn @ mkn^T) over active slots, partial row sums
  k_gemm_bt<1><<<dim3(32, 128), 256, 0, stream>>>(qn, mkn, 4096, 512,
      meta, nullptr, P, nullptr, lpart, nullptr);
  k_reduce_l<<<64, 256, 0, stream>>>(lpart, linv, meta);

  // retrieved = (P @ Vt^T) * linv[row]  bf16   (K-loop trips = meta[2])
  k_gemm_bt<2><<<dim3(4, 128), 256, 0, stream>>>(P, vt, 512, 4096,
      meta, nullptr, retr, nullptr, nullptr, linv);

  // out = retrieved @ Wo^T + bo  (fp32)
  k_gemm_bt<0><<<dim3(4, 128), 256, 0, stream>>>(retr, wob, 512, 512,
      nullptr, (float*)d_out, nullptr, bo, nullptr, nullptr);
}